// Round 8
// baseline (93.090 us; speedup 1.0000x reference)
//
#include <hip/hip_runtime.h>
#include <hip/hip_bf16.h>

// Problem constants
#define DD 512
#define HIDN 64
#define NTREE 64
#define NIN 7           // internal nodes
#define PPTC 3607       // NI*D + NI + NL*2
#define TOTP 230912     // PPT*T + T
#define SWROWS 448      // T*NI

typedef __attribute__((ext_vector_type(8))) short bf16x8;
typedef __attribute__((ext_vector_type(4))) float f32x4;
typedef __attribute__((ext_vector_type(8))) _Float16 h16x8;

__device__ __forceinline__ unsigned short f2bf(float f) {
  unsigned u = __float_as_uint(f);
  unsigned r = (u + 0x7FFFu + ((u >> 16) & 1u)) >> 16;   // RNE
  return (unsigned short)r;
}
__device__ __forceinline__ float sigmoidf_(float x) {
  return 1.0f / (1.0f + __expf(-x));
}
__device__ __forceinline__ uint2 pack_bf16x4(float4 v) {
  uint2 pk;
  pk.x = (unsigned)f2bf(v.x) | ((unsigned)f2bf(v.y) << 16);
  pk.y = (unsigned)f2bf(v.z) | ((unsigned)f2bf(v.w) << 16);
  return pk;
}
// 8 fp32 -> bf16x8 via HW packed convert (RNE)
__device__ __forceinline__ bf16x8 cvt8(float4 a, float4 b) {
  unsigned u0, u1, u2, u3;
  asm("v_cvt_pk_bf16_f32 %0, %1, %2" : "=v"(u0) : "v"(a.x), "v"(a.y));
  asm("v_cvt_pk_bf16_f32 %0, %1, %2" : "=v"(u1) : "v"(a.z), "v"(a.w));
  asm("v_cvt_pk_bf16_f32 %0, %1, %2" : "=v"(u2) : "v"(b.x), "v"(b.y));
  asm("v_cvt_pk_bf16_f32 %0, %1, %2" : "=v"(u3) : "v"(b.z), "v"(b.w));
  union { unsigned u[4]; bf16x8 v; } r;
  r.u[0] = u0; r.u[1] = u1; r.u[2] = u2; r.u[3] = u3;
  return r.v;
}
// async global->LDS, 16B per lane
__device__ __forceinline__ void gl_lds16(const void* g, void* l) {
  __builtin_amdgcn_global_load_lds(
      (const __attribute__((address_space(1))) unsigned int*)g,
      (__attribute__((address_space(3))) unsigned int*)l, 16, 0, 0);
}

// ---------------------------------------------------------------------------
// Kernel 1: train path. 256 blocks x 256 thr (4 waves), 32 rows/block.
// (unchanged — known-good)
// ---------------------------------------------------------------------------
__global__ __launch_bounds__(256) void k_train(
    const float* __restrict__ Xtr, const float* __restrict__ W1,
    const float* __restrict__ b1, const float* __restrict__ g1,
    const float* __restrict__ be1, const float* __restrict__ W2,
    const float* __restrict__ b2, float* __restrict__ c_part)
{
  __shared__ __align__(16) char smem[37888];
  char* Xc  = smem;
  char* W1c = smem + 8192;
  char* Hl  = smem + 24576;
  char* W2l = smem + 28672;
  float* lnb = (float*)(smem + 36864);
  float* cp  = (float*)(smem + 37376);

  const int tid = threadIdx.x;
  const int lane = tid & 63;
  const int wv = tid >> 6;
  const int l15 = lane & 15;
  const int gq = lane >> 4;
  const int wm = wv >> 1;
  const int wn = wv & 1;
  const int rb0 = blockIdx.x * 32;

  const float4* X4g = (const float4*)Xtr;
  const float4* W4g = (const float4*)W1;

#pragma unroll
  for (int s = 0; s < 4; ++s) {
    int fidx = tid + s * 256;
    int n = fidx >> 4, kq = fidx & 15;
    float4 v = ((const float4*)W2)[n * 16 + kq];
    uint2 pk = pack_bf16x4(v);
    int off = n * 128 + kq * 8; off ^= (n & 7) << 4;
    *(uint2*)(W2l + off) = pk;
  }

  int xga[4], xo[4];
#pragma unroll
  for (int s = 0; s < 4; ++s) {
    int f = tid + s * 256;
    int m = f >> 5, kq = f & 31;
    xga[s] = (rb0 + m) * 128 + kq;
    xo[s] = (m * 256 + kq * 8) ^ ((m & 7) << 4);
  }
  int wga[8], wo[8];
#pragma unroll
  for (int s = 0; s < 8; ++s) {
    int f = tid + s * 256;
    int n = f >> 5, kq = f & 31;
    wga[s] = n * 128 + kq;
    wo[s] = (n * 256 + kq * 8) ^ ((n & 7) << 4);
  }

  f32x4 acc1[2];
#pragma unroll
  for (int nt = 0; nt < 2; ++nt) { f32x4 z = {0.f,0.f,0.f,0.f}; acc1[nt] = z; }

  float4 xr[4], wr[8];
#pragma unroll
  for (int s = 0; s < 4; ++s) xr[s] = X4g[xga[s]];
#pragma unroll
  for (int s = 0; s < 8; ++s) wr[s] = W4g[wga[s]];

  for (int kc = 0; kc < 4; ++kc) {
    __syncthreads();
#pragma unroll
    for (int s = 0; s < 4; ++s) *(uint2*)(Xc + xo[s]) = pack_bf16x4(xr[s]);
#pragma unroll
    for (int s = 0; s < 8; ++s) *(uint2*)(W1c + wo[s]) = pack_bf16x4(wr[s]);
    if (kc < 3) {
      int ko = (kc + 1) * 32;
#pragma unroll
      for (int s = 0; s < 4; ++s) xr[s] = X4g[xga[s] + ko];
#pragma unroll
      for (int s = 0; s < 8; ++s) wr[s] = W4g[wga[s] + ko];
    }
    __syncthreads();
#pragma unroll
    for (int ks = 0; ks < 4; ++ks) {
      int arow = wm * 16 + l15;
      int aoff = (arow * 256 + ks * 64 + gq * 16) ^ ((arow & 7) << 4);
      bf16x8 afr = *(const bf16x8*)(Xc + aoff);
#pragma unroll
      for (int nt = 0; nt < 2; ++nt) {
        int brow = wn * 32 + nt * 16 + l15;
        int boff = (brow * 256 + ks * 64 + gq * 16) ^ ((brow & 7) << 4);
        bf16x8 bfr = *(const bf16x8*)(W1c + boff);
        acc1[nt] = __builtin_amdgcn_mfma_f32_16x16x32_bf16(afr, bfr, acc1[nt], 0, 0, 0);
      }
    }
  }

  float b1v[2], g1v[2], be1v[2], b2v[2];
#pragma unroll
  for (int nt = 0; nt < 2; ++nt) {
    int c = wn * 32 + nt * 16 + l15;
    b1v[nt] = b1[c]; g1v[nt] = g1[c]; be1v[nt] = be1[c]; b2v[nt] = b2[c];
  }
  float yv[2][4], s_[4], q_[4];
#pragma unroll
  for (int i = 0; i < 4; ++i) {
    float s = 0.f, q = 0.f;
#pragma unroll
    for (int nt = 0; nt < 2; ++nt) {
      float y = acc1[nt][i] + b1v[nt];
      yv[nt][i] = y; s += y; q += y * y;
    }
    s_[i] = s; q_[i] = q;
  }
#pragma unroll
  for (int off = 1; off < 16; off <<= 1) {
#pragma unroll
    for (int i = 0; i < 4; ++i) {
      s_[i] += __shfl_xor(s_[i], off);
      q_[i] += __shfl_xor(q_[i], off);
    }
  }
  if (l15 == 0) {
#pragma unroll
    for (int i = 0; i < 4; ++i) {
      int row = wm * 16 + gq * 4 + i;
      float2 sv; sv.x = s_[i]; sv.y = q_[i];
      *(float2*)(lnb + (row * 2 + wn) * 2) = sv;
    }
  }
  __syncthreads();
#pragma unroll
  for (int i = 0; i < 4; ++i) {
    int row = wm * 16 + gq * 4 + i;
    float2 e0 = *(float2*)(lnb + (row * 2 + 0) * 2);
    float2 e1 = *(float2*)(lnb + (row * 2 + 1) * 2);
    float m = (e0.x + e1.x) * (1.0f / 64.0f);
    float var = (e0.y + e1.y) * (1.0f / 64.0f) - m * m;
    float rstd = rsqrtf(var + 1e-5f);
#pragma unroll
    for (int nt = 0; nt < 2; ++nt) {
      float h = (yv[nt][i] - m) * rstd * g1v[nt] + be1v[nt];
      h = fmaxf(h, 0.0f);
      int col = wn * 32 + nt * 16 + l15;
      int off2 = (row * 128 + col * 2) ^ ((row & 7) << 4);
      *(unsigned short*)(Hl + off2) = f2bf(h);
    }
  }
  __syncthreads();

  f32x4 acc2[2];
#pragma unroll
  for (int nt = 0; nt < 2; ++nt) { f32x4 z = {0.f,0.f,0.f,0.f}; acc2[nt] = z; }
#pragma unroll
  for (int ks = 0; ks < 2; ++ks) {
    int arow = wm * 16 + l15;
    int aoff = (arow * 128 + ks * 64 + gq * 16) ^ ((arow & 7) << 4);
    bf16x8 afr = *(const bf16x8*)(Hl + aoff);
#pragma unroll
    for (int nt = 0; nt < 2; ++nt) {
      int brow = wn * 32 + nt * 16 + l15;
      int boff = (brow * 128 + ks * 64 + gq * 16) ^ ((brow & 7) << 4);
      bf16x8 bfr = *(const bf16x8*)(W2l + boff);
      acc2[nt] = __builtin_amdgcn_mfma_f32_16x16x32_bf16(afr, bfr, acc2[nt], 0, 0, 0);
    }
  }
  float cs[2];
#pragma unroll
  for (int nt = 0; nt < 2; ++nt) {
    float s = 0.f;
#pragma unroll
    for (int i = 0; i < 4; ++i) s += fmaxf(acc2[nt][i] + b2v[nt], 0.0f);
    cs[nt] = s;
  }
#pragma unroll
  for (int nt = 0; nt < 2; ++nt) {
    cs[nt] += __shfl_xor(cs[nt], 16);
    cs[nt] += __shfl_xor(cs[nt], 32);
  }
  if (lane < 16) {
#pragma unroll
    for (int nt = 0; nt < 2; ++nt)
      cp[wm * 64 + wn * 32 + nt * 16 + lane] = cs[nt];
  }
  __syncthreads();
  if (tid < 64) c_part[blockIdx.x * 64 + tid] = cp[tid] + cp[64 + tid];
}

// ---------------------------------------------------------------------------
// Kernel 2: reduce c partials + head MLP. 1 block x 256 threads. (unchanged)
// ---------------------------------------------------------------------------
__global__ __launch_bounds__(256) void k_head(
    const float* __restrict__ c_part,
    const float* __restrict__ H1, const float* __restrict__ hb1,
    const float* __restrict__ g2, const float* __restrict__ be2,
    const float* __restrict__ H2, const float* __restrict__ hb2,
    float* __restrict__ u2out)
{
  __shared__ float part[256];
  __shared__ float clds[64];
  __shared__ float u1lds[128];
  __shared__ float red[8];
  int tid = threadIdx.x;
  {
    int col = tid & 63, g = tid >> 6;
    float s0 = 0.f, s1 = 0.f, s2 = 0.f, s3 = 0.f;
    int b0 = g * 64;
    for (int b = 0; b < 64; b += 4) {
      s0 += c_part[(b0 + b + 0) * 64 + col];
      s1 += c_part[(b0 + b + 1) * 64 + col];
      s2 += c_part[(b0 + b + 2) * 64 + col];
      s3 += c_part[(b0 + b + 3) * 64 + col];
    }
    part[tid] = (s0 + s1) + (s2 + s3);
  }
  __syncthreads();
  if (tid < 64)
    clds[tid] = (part[tid] + part[64 + tid] + part[128 + tid] + part[192 + tid]) * (1.0f / 8192.0f);
  __syncthreads();
  float acc = 0.f;
  if (tid < 128) {
    float a0 = 0.f, a1 = 0.f, a2 = 0.f, a3 = 0.f;
    for (int k = 0; k < 64; k += 4) {
      a0 += clds[k + 0] * H1[tid * 64 + k + 0];
      a1 += clds[k + 1] * H1[tid * 64 + k + 1];
      a2 += clds[k + 2] * H1[tid * 64 + k + 2];
      a3 += clds[k + 3] * H1[tid * 64 + k + 3];
    }
    acc = hb1[tid] + ((a0 + a1) + (a2 + a3));
  }
  float s = acc, q = acc * acc;
#pragma unroll
  for (int off = 1; off < 64; off <<= 1) { s += __shfl_xor(s, off); q += __shfl_xor(q, off); }
  int wv = tid >> 6;
  if ((tid & 63) == 0) { red[wv * 2] = s; red[wv * 2 + 1] = q; }
  __syncthreads();
  float S = red[0] + red[2], Q = red[1] + red[3];
  float m = S * (1.0f / 128.0f);
  float var = Q * (1.0f / 128.0f) - m * m;
  float rstd = rsqrtf(var + 1e-5f);
  if (tid < 128)
    u1lds[tid] = fmaxf((acc - m) * rstd * g2[tid] + be2[tid], 0.0f);
  __syncthreads();
  if (tid < 128) {
    float c0 = 0.f, c1 = 0.f, c2 = 0.f, c3 = 0.f;
    for (int k = 0; k < 128; k += 4) {
      c0 += u1lds[k + 0] * H2[tid * 128 + k + 0];
      c1 += u1lds[k + 1] * H2[tid * 128 + k + 1];
      c2 += u1lds[k + 2] * H2[tid * 128 + k + 2];
      c3 += u1lds[k + 3] * H2[tid * 128 + k + 3];
    }
    u2out[tid] = fmaxf(hb2[tid] + ((c0 + c1) + (c2 + c3)), 0.0f);
  }
}

// ---------------------------------------------------------------------------
// Kernel 3: params = u2 @ H3^T + hb3, routed to Bfrag / sb / ll / tw.
// Bfrag (u16 idx): (half*16 + kt)*8192 + (kgq*256 + colp)*8 + j
//   half = t>>5, colp = (t&31)*7 + n (0..223, pad to 256), kt = d>>5,
//   kgq = (d>>3)&3, j = d&7.  Per-(half,kt) tile = 16 KB contiguous.
// Also zeroes d_out (blocks 0..255) for k_test's atomicAdd epilogue.
// ---------------------------------------------------------------------------
__global__ __launch_bounds__(256) void k_params(
    const float* __restrict__ H3, const float* __restrict__ hb3,
    const float* __restrict__ u2,
    unsigned short* __restrict__ Bfrag, float* __restrict__ sb,
    float* __restrict__ ll, float* __restrict__ tw,
    float* __restrict__ outz)
{
  __shared__ float u2l[128];
  int tid = threadIdx.x;
  if (tid < 128) u2l[tid] = u2[tid];
  if (blockIdx.x < 256) outz[blockIdx.x * 256 + tid] = 0.0f;
  __syncthreads();
  int row = blockIdx.x * 64 + (tid >> 2);
  int sub = tid & 3;
  float acc = 0.0f;
  const float4* H4 = (const float4*)H3;
#pragma unroll
  for (int j = 0; j < 8; ++j) {
    int f = j * 4 + sub;
    float4 v = H4[row * 32 + f];
    acc += v.x * u2l[f * 4] + v.y * u2l[f * 4 + 1] + v.z * u2l[f * 4 + 2] + v.w * u2l[f * 4 + 3];
  }
  acc += __shfl_xor(acc, 1);
  acc += __shfl_xor(acc, 2);
  if (sub == 0) {
    float val = acc + hb3[row];
    if (row >= 230848) {
      tw[row - 230848] = val;
    } else {
      int t = row / PPTC;
      int r = row - t * PPTC;
      if (r < 3584) {
        int n = r >> 9, d = r & 511;
        int half = t >> 5;
        int colp = (t & 31) * 7 + n;
        int kt = d >> 5, kgq = (d >> 3) & 3, j = d & 7;
        Bfrag[(half * 16 + kt) * 8192 + (kgq * 256 + colp) * 8 + j] = f2bf(val);
      } else if (r < 3591) {
        sb[t * 7 + (r - 3584)] = val;
      } else {
        ll[t * 16 + (r - 3591)] = val;
      }
    }
  }
}

// ---------------------------------------------------------------------------
// Kernel 4: main inference. 512 blocks x 256 thr (4 waves). BM=128, BN=224
// (one tree-aligned N-half per block), BK=32, 16 K-tiles. 2 blocks/CU for
// cross-block wave overlap (m114). Ring-2 gl_lds staging (32 KB tiles),
// counted vmcnt(8), raw barriers. B LDS [kgq][colp] — conflict-free reads +
// coalesced producer-ordered staging. X: row-major granule-XOR (r7 scheme).
// Per-block 32-tree partials combined into d_out via fp32 atomicAdd
// (commutative -> deterministic; d_out zeroed by k_params).
// ---------------------------------------------------------------------------
__global__ __launch_bounds__(256, 2) void k_test(
    const float* __restrict__ Xt, const unsigned short* __restrict__ Bfrag,
    const float* __restrict__ sb, const float* __restrict__ ll,
    const float* __restrict__ tw, float* __restrict__ out)
{
  // ring: 2 x (X 16384 + B 16384) = 65536 ; qlds 2048 ; sbl 896
  __shared__ __align__(16) char smem[68608];
  char* Pl = smem;                          // tree-phase alias (16 KB)
  float* qlds = (float*)(smem + 65536);     // 32 trees x 16
  float* sbl  = (float*)(smem + 67584);     // 224 f32

  const int tid = threadIdx.x;
  const int lane = tid & 63;
  const int wv = tid >> 6;            // 0..3
  const int l15 = lane & 15;
  const int gq = lane >> 4;
  const int wm = wv >> 1;             // 0..1 (64-row group)
  const int wn = wv & 1;              // 0..1 (112-col group)
  // XCD pairing: halves of the same M-block land on the same XCD (ids differ by 8)
  const int bx = blockIdx.x;
  const int mblk = (bx >> 4) * 8 + (bx & 7);
  const int half = (bx >> 3) & 1;
  const int bm0 = mblk * 128;
  const int T0 = half * 32;           // first tree of this block

  const float4* X4 = (const float4*)Xt;
  const char* Bf = (const char*)Bfrag + half * 262144;   // this half's 16 tiles

  // ---- prologue: sb slice -> LDS; qprep (softmax over all 64 trees) ----
  if (tid < 224) sbl[tid] = sb[T0 * 7 + tid];
  if (tid < 64) {
    int t = tid;
    float x = tw[t];
    float m = x;
#pragma unroll
    for (int off = 1; off < 64; off <<= 1) m = fmaxf(m, __shfl_xor(m, off));
    float e = __expf(x - m);
    float s = e;
#pragma unroll
    for (int off = 1; off < 64; off <<= 1) s += __shfl_xor(s, off);
    float w = e / s;
    if ((t >> 5) == half) {
      int lt = t & 31;
#pragma unroll
      for (int l = 0; l < 8; ++l) {
        float a = ll[t * 16 + l * 2], b = ll[t * 16 + l * 2 + 1];
        float mm = fmaxf(a, b);
        float e0 = __expf(a - mm), e1 = __expf(b - mm);
        float inv = 2.0f * w / (e0 + e1);
        qlds[lt * 16 + l * 2] = e0 * inv;
        qlds[lt * 16 + l * 2 + 1] = e1 * inv;
      }
    }
  }

  // X staging (4 slots/thread): slot = tid + s*256; row = slot>>3 (0..127),
  // p_lds = tid&7, global granule pg = p_lds ^ (row&7) (pre-swizzled source).
  int xsrc[4];
#pragma unroll
  for (int s = 0; s < 4; ++s) {
    int row = (tid >> 3) + s * 32;
    int pg = (tid & 7) ^ (row & 7);
    xsrc[s] = (bm0 + row) * 128 + pg;        // + kt*8 (float4 idx)
  }

#define ISSUE_TILE(t_) do { \
    char* xb_ = smem + ((t_) & 1) * 32768; \
    char* bb_ = xb_ + 16384; \
    gl_lds16(X4 + (xsrc[0] + (t_) * 8), xb_ + tid * 16); \
    gl_lds16(X4 + (xsrc[1] + (t_) * 8), xb_ + (tid + 256) * 16); \
    gl_lds16(X4 + (xsrc[2] + (t_) * 8), xb_ + (tid + 512) * 16); \
    gl_lds16(X4 + (xsrc[3] + (t_) * 8), xb_ + (tid + 768) * 16); \
    const char* bt_ = Bf + (t_) * 16384; \
    gl_lds16(bt_ + tid * 16,          bb_ + tid * 16); \
    gl_lds16(bt_ + (tid + 256) * 16,  bb_ + (tid + 256) * 16); \
    gl_lds16(bt_ + (tid + 512) * 16,  bb_ + (tid + 512) * 16); \
    gl_lds16(bt_ + (tid + 768) * 16,  bb_ + (tid + 768) * 16); \
  } while (0)

  f32x4 acc[4][7];
#pragma unroll
  for (int mt = 0; mt < 4; ++mt)
#pragma unroll
    for (int nt = 0; nt < 7; ++nt) { f32x4 z = {0.f,0.f,0.f,0.f}; acc[mt][nt] = z; }

  // frag-read offsets
  const int xoff0 = (((2 * gq) ^ (l15 & 7)) << 4);
  const int xoff1 = (((2 * gq + 1) ^ (l15 & 7)) << 4);
  int arow[4];
#pragma unroll
  for (int mt = 0; mt < 4; ++mt) arow[mt] = (wm * 64 + mt * 16 + l15) * 128;
  int boffs[7];
#pragma unroll
  for (int nt = 0; nt < 7; ++nt)
    boffs[nt] = (gq * 256 + wn * 112 + nt * 16 + l15) * 16;

#define COMPUTE_TILE(t_) do { \
    char* xb_ = smem + ((t_) & 1) * 32768; \
    char* bb_ = xb_ + 16384; \
    bf16x8 abf[4]; \
    _Pragma("unroll") \
    for (int mt = 0; mt < 4; ++mt) { \
      float4 a0 = *(const float4*)(xb_ + arow[mt] + xoff0); \
      float4 a1 = *(const float4*)(xb_ + arow[mt] + xoff1); \
      abf[mt] = cvt8(a0, a1); \
    } \
    _Pragma("unroll") \
    for (int nt = 0; nt < 7; ++nt) { \
      bf16x8 bfr = *(const bf16x8*)(bb_ + boffs[nt]); \
      _Pragma("unroll") \
      for (int mt = 0; mt < 4; ++mt) \
        acc[mt][nt] = __builtin_amdgcn_mfma_f32_16x16x32_bf16(abf[mt], bfr, acc[mt][nt], 0, 0, 0); \
    } } while (0)

  // prologue: fill both buffers (16 loads/thread in flight)
  ISSUE_TILE(0);
  ISSUE_TILE(1);
  asm volatile("s_waitcnt lgkmcnt(0)" ::: "memory");   // qlds/sbl writes done

#pragma unroll 1
  for (int t = 0; t < 15; ++t) {
    asm volatile("s_waitcnt vmcnt(8)" ::: "memory");   // tile t landed; t+1 in flight
    __builtin_amdgcn_sched_barrier(0);
    __builtin_amdgcn_s_barrier();
    COMPUTE_TILE(t);
    __builtin_amdgcn_s_barrier();                      // buf[t&1] free
    if (t < 14) ISSUE_TILE(t + 2);
  }
  asm volatile("s_waitcnt vmcnt(0)" ::: "memory");
  __builtin_amdgcn_sched_barrier(0);
  __builtin_amdgcn_s_barrier();
  COMPUTE_TILE(15);
  __syncthreads();   // drain before tree phase aliases the ring

  // q into registers: lane (0..31) <-> local tree; lanes 32..63 contribute 0
  float qreg[16];
  {
    const float4* q4 = (const float4*)qlds;
    int lt = lane & 31;
#pragma unroll
    for (int j = 0; j < 4; ++j) {
      float4 v = q4[lt * 4 + j];
      bool lo = (lane < 32);
      qreg[j * 4]     = lo ? v.x : 0.f;
      qreg[j * 4 + 1] = lo ? v.y : 0.f;
      qreg[j * 4 + 2] = lo ? v.z : 0.f;
      qreg[j * 4 + 3] = lo ? v.w : 0.f;
    }
  }

  // ---- fused sigmoid + soft-tree + mixing, 4 passes of 32 rows ----
  // P layout: [32 rows][32 trees][8 slots] f16 -> row stride 512 B.
#pragma unroll
  for (int rg = 0; rg < 4; ++rg) {
    if (wm == (rg >> 1)) {
#pragma unroll
      for (int mtl = 0; mtl < 2; ++mtl) {
        const int mt = (rg & 1) * 2 + mtl;
#pragma unroll
        for (int nt = 0; nt < 7; ++nt) {
          int col = wn * 112 + nt * 16 + l15;   // 0..223
          float sbv = sbl[col];
          int lt = col / 7;
          int jj = col - lt * 7;
          int slot2 = (lt * 8 + jj) * 2;
#pragma unroll
          for (int i = 0; i < 4; ++i) {
            int rl = mtl * 16 + gq * 4 + i;
            float p = sigmoidf_(acc[mt][nt][i] + sbv);
            *(_Float16*)(Pl + rl * 512 + slot2) = (_Float16)p;
          }
        }
      }
    }
    __syncthreads();
#pragma unroll
    for (int k = 0; k < 8; ++k) {
      int rl = wv * 8 + k;
      h16x8 v = *(const h16x8*)(Pl + rl * 512 + (lane & 31) * 16);
      float p0 = (float)v[0], p1 = (float)v[1], p2 = (float)v[2];
      float p3 = (float)v[3], p4 = (float)v[4], p5 = (float)v[5], p6 = (float)v[6];
      float n0 = 1.f - p0, n1 = 1.f - p1, n2 = 1.f - p2;
      float a00 = n0 * n1, a01 = n0 * p1, a10 = p0 * n2, a11 = p0 * p2;
      float L0 = a00 * (1.f - p3), L1 = a00 * p3;
      float L2 = a01 * (1.f - p4), L3 = a01 * p4;
      float L4 = a10 * (1.f - p5), L5 = a10 * p5;
      float L6 = a11 * (1.f - p6), L7 = a11 * p6;
      float o0 = L0*qreg[0] + L1*qreg[2] + L2*qreg[4] + L3*qreg[6]
               + L4*qreg[8] + L5*qreg[10] + L6*qreg[12] + L7*qreg[14];
      float o1 = L0*qreg[1] + L1*qreg[3] + L2*qreg[5] + L3*qreg[7]
               + L4*qreg[9] + L5*qreg[11] + L6*qreg[13] + L7*qreg[15];
#pragma unroll
      for (int off = 1; off < 64; off <<= 1) {
        o0 += __shfl_xor(o0, off);
        o1 += __shfl_xor(o1, off);
      }
      if (lane == 0) {
        int gr = bm0 + rg * 32 + rl;
        atomicAdd(&out[gr * 2], o0);
        atomicAdd(&out[gr * 2 + 1], o1);
      }
    }
    __syncthreads();
  }
#undef ISSUE_TILE
#undef COMPUTE_TILE
}

// ---------------------------------------------------------------------------
extern "C" void kernel_launch(void* const* d_in, const int* in_sizes, int n_in,
                              void* d_out, int out_size, void* d_ws, size_t ws_size,
                              hipStream_t stream)
{
  const float* Xtr = (const float*)d_in[0];
  const float* Xte = (const float*)d_in[1];
  const float* W1  = (const float*)d_in[3];
  const float* b1  = (const float*)d_in[4];
  const float* g1  = (const float*)d_in[5];
  const float* be1 = (const float*)d_in[6];
  const float* W2  = (const float*)d_in[7];
  const float* b2  = (const float*)d_in[8];
  const float* H1  = (const float*)d_in[9];
  const float* hb1 = (const float*)d_in[10];
  const float* g2  = (const float*)d_in[11];
  const float* be2 = (const float*)d_in[12];
  const float* H2  = (const float*)d_in[13];
  const float* hb2 = (const float*)d_in[14];
  const float* H3  = (const float*)d_in[15];
  const float* hb3 = (const float*)d_in[16];
  float* out = (float*)d_out;
  char* ws = (char*)d_ws;

  float* c_part = (float*)ws;                  // 256*64 f32 = 65536 B
  float* u2     = (float*)(ws + 65536);        // 128 f32
  float* sb     = (float*)(ws + 66048);        // 448 f32
  float* ll     = (float*)(ws + 67840);        // 1024 f32
  float* tw     = (float*)(ws + 71936);        // 64 f32
  unsigned short* Bfrag = (unsigned short*)(ws + 72192); // 2 halves x 16 tiles x 16 KB = 524288 B

  k_train<<<256, 256, 0, stream>>>(Xtr, W1, b1, g1, be1, W2, b2, c_part);
  k_head<<<1, 256, 0, stream>>>(c_part, H1, hb1, g2, be2, H2, hb2, u2);
  k_params<<<3608, 256, 0, stream>>>(H3, hb3, u2, Bfrag, sb, ll, tw, out);
  k_test<<<512, 256, 0, stream>>>(Xte, Bfrag, sb, ll, tw, out);
}